// Round 4
// baseline (669.530 us; speedup 1.0000x reference)
//
#include <hip/hip_runtime.h>
#include <hip/hip_bf16.h>

// Grouped GEMM: out[e,s,o] = sum_i x[e,s,i] * w[e,o,i]
// E=8, S=8192 tok/expert, O=512, I=1024, fp32 in/out, bf16 MFMA compute.
// R4: raw s_barrier (lgkmcnt(0) only -- global loads stay in flight across
//     the barrier, T4-lite) + register double-buffered B fragments.

#define NE 8
#define NO 512
#define NI 1024
#define NS 8192

#define BM 128
#define BN 128
#define BK 64
#define NT (NI / BK)  // 16 K-steps

typedef __attribute__((ext_vector_type(4))) float f32x4;
typedef __attribute__((ext_vector_type(8))) short short8;

__device__ __forceinline__ short8 cvt8(f32x4 a, f32x4 b) {
    short8 r;
    r[0] = (short)__builtin_bit_cast(unsigned short, __float2bfloat16(a[0]));
    r[1] = (short)__builtin_bit_cast(unsigned short, __float2bfloat16(a[1]));
    r[2] = (short)__builtin_bit_cast(unsigned short, __float2bfloat16(a[2]));
    r[3] = (short)__builtin_bit_cast(unsigned short, __float2bfloat16(a[3]));
    r[4] = (short)__builtin_bit_cast(unsigned short, __float2bfloat16(b[0]));
    r[5] = (short)__builtin_bit_cast(unsigned short, __float2bfloat16(b[1]));
    r[6] = (short)__builtin_bit_cast(unsigned short, __float2bfloat16(b[2]));
    r[7] = (short)__builtin_bit_cast(unsigned short, __float2bfloat16(b[3]));
    return r;
}

// ---- pass 0: W fp32 -> bf16, MFMA B-fragment lane order (verified R3) ----
__global__ __launch_bounds__(256)
void pack_w(const float* __restrict__ W, short* __restrict__ Wpk) {
    int idx  = blockIdx.x * 256 + threadIdx.x;  // 0 .. 524287
    int l    = idx & 63;
    int kt32 = (idx >> 6) & 31;
    int g    = (idx >> 11) & 31;
    int e    = idx >> 16;
    const float* src = W + (size_t)(e * NO + g * 16 + (l & 15)) * NI
                         + kt32 * 32 + (l >> 4) * 8;
    f32x4 a = *(const f32x4*)src;
    f32x4 b = *(const f32x4*)(src + 4);
    *(short8*)(Wpk + (size_t)idx * 8) = cvt8(a, b);
}

// ---- main grouped GEMM ----
__global__ __launch_bounds__(256, 3)
void moe_gemm(const float* __restrict__ X,
              const short* __restrict__ Wpk,
              float* __restrict__ Out) {
    // 2048 blocks; XCD-chunk swizzle: each XCD owns one expert (W L2-resident).
    int bid  = blockIdx.x;
    int swz  = (bid & 7) * 256 + (bid >> 3);
    int e    = swz >> 8;
    int rem  = swz & 255;
    int mblk = rem >> 2;   // nblk inner: 4 siblings share the same A tile
    int nblk = rem & 3;

    const float* Ap = X   + ((size_t)e * NS + (size_t)mblk * BM) * NI;
    const short* Bp = Wpk + (size_t)e * (32 * 32 * 64 * 8);
    float*       Cp = Out + ((size_t)e * NS + (size_t)mblk * BM) * NO + nblk * BN;

    __shared__ short lA[2][BM * BK];   // 16 KiB per buf

    const int tid  = threadIdx.x;
    const int lane = tid & 63;
    const int wid  = tid >> 6;
    const int wr   = (wid >> 1) * 64;            // wave row base (2x2 wave grid)
    const int wc   = (wid & 1) * 64;             // wave col base
    const int wcg  = nblk * 8 + (wid & 1) * 4;   // B fragment-group base
    const int l15  = lane & 15;
    const int l4   = lane >> 4;

    f32x4 acc[4][4];
#pragma unroll
    for (int i = 0; i < 4; ++i)
#pragma unroll
        for (int j = 0; j < 4; ++j)
            acc[i][j] = (f32x4){0.f, 0.f, 0.f, 0.f};

    // A staging: unit u = tid + i*256, row = u>>3, chunk = u&7, swz phys = c ^ (row&7).
    int ur[4], ucc[4], wofs[4];
#pragma unroll
    for (int i = 0; i < 4; ++i) {
        int u   = tid + i * 256;
        ur[i]   = u >> 3;
        ucc[i]  = u & 7;
        wofs[i] = ur[i] * BK + ((ucc[i] ^ (ur[i] & 7)) << 3);
    }

    f32x4 la[4][2];
    short8 bfrA[2][4], bfrB[2][4];   // named double-buffer (rule #20: no runtime idx)

#define LOADT(kt)                                                              \
    do {                                                                       \
        _Pragma("unroll") for (int i = 0; i < 4; ++i) {                        \
            const f32x4* p = (const f32x4*)(Ap + (size_t)ur[i] * NI +          \
                                            (kt) * BK + ucc[i] * 8);           \
            la[i][0] = p[0];                                                   \
            la[i][1] = p[1];                                                   \
        }                                                                      \
    } while (0)

#define STAGE(buf)                                                             \
    do {                                                                       \
        _Pragma("unroll") for (int i = 0; i < 4; ++i)                          \
            *(short8*)&lA[buf][wofs[i]] = cvt8(la[i][0], la[i][1]);            \
    } while (0)

#define BLOAD(kt, dst)                                                         \
    do {                                                                       \
        _Pragma("unroll") for (int kk = 0; kk < 2; ++kk)                       \
            _Pragma("unroll") for (int ni = 0; ni < 4; ++ni)                   \
                dst[kk][ni] = *(const short8*)(Bp +                            \
                    ((size_t)((wcg + ni) * 32 + (kt) * 2 + kk) * 64 + lane) * 8); \
    } while (0)

#define COMPUTE(buf, bfr)                                                      \
    do {                                                                       \
        _Pragma("unroll") for (int kk = 0; kk < 2; ++kk) {                     \
            short8 af[4];                                                      \
            _Pragma("unroll") for (int mi = 0; mi < 4; ++mi) {                 \
                int row = wr + mi * 16 + l15;                                  \
                int cc  = ((kk * 4 + l4) ^ (row & 7)) << 3;                    \
                af[mi]  = *(const short8*)&lA[buf][row * BK + cc];             \
            }                                                                  \
            _Pragma("unroll") for (int mi = 0; mi < 4; ++mi)                   \
                _Pragma("unroll") for (int ni = 0; ni < 4; ++ni)               \
                    acc[mi][ni] = __builtin_amdgcn_mfma_f32_16x16x32_bf16(     \
                        af[mi], bfr[kk][ni], acc[mi][ni], 0, 0, 0);            \
        }                                                                      \
    } while (0)

// lgkmcnt(0): LDS writes visible; global loads stay in flight across barrier.
#define LBAR()                                                                 \
    do {                                                                       \
        asm volatile("s_waitcnt lgkmcnt(0)" ::: "memory");                     \
        __builtin_amdgcn_s_barrier();                                          \
    } while (0)

    // Prologue: A(0) -> lds0, B(0) -> bfrA.
    LOADT(0);
    BLOAD(0, bfrA);
    STAGE(0);
    LBAR();

#pragma unroll 1
    for (int kt2 = 0; kt2 < NT / 2; ++kt2) {
        const int kt = kt2 * 2;
        // even step: compute lds0/bfrA, prefetch kt+1 into la/bfrB
        LOADT(kt + 1);            // A: HBM, issued first (oldest)
        BLOAD(kt + 1, bfrB);      // B: L2
        COMPUTE(0, bfrA);
        STAGE(1);                 // waits la only (counted vmcnt, B in flight)
        LBAR();
        // odd step: compute lds1/bfrB, prefetch kt+2 into la/bfrA
        if (kt2 < NT / 2 - 1) {
            LOADT(kt + 2);
            BLOAD(kt + 2, bfrA);
            COMPUTE(1, bfrB);
            STAGE(0);
            LBAR();
        } else {
            COMPUTE(1, bfrB);     // last tile: no prefetch, no barrier needed
        }
    }

    // Epilogue: D[m][n], m = (lane>>4)*4 + r, n = lane&15 within each 16x16 frag.
#pragma unroll
    for (int mi = 0; mi < 4; ++mi) {
#pragma unroll
        for (int r = 0; r < 4; ++r) {
            int row   = wr + mi * 16 + l4 * 4 + r;
            float* cp = Cp + (size_t)row * NO + wc + l15;
#pragma unroll
            for (int ni = 0; ni < 4; ++ni)
                cp[ni * 16] = acc[mi][ni][r];
        }
    }
#undef LOADT
#undef STAGE
#undef BLOAD
#undef COMPUTE
#undef LBAR
}

extern "C" void kernel_launch(void* const* d_in, const int* in_sizes, int n_in,
                              void* d_out, int out_size, void* d_ws, size_t ws_size,
                              hipStream_t stream) {
    const float* X = (const float*)d_in[0];
    const float* W = (const float*)d_in[1];
    float* Out     = (float*)d_out;
    short* Wpk     = (short*)d_ws;   // needs 8 MiB

    hipLaunchKernelGGL(pack_w, dim3(2048), dim3(256), 0, stream, W, Wpk);
    hipLaunchKernelGGL(moe_gemm, dim3(NE * (NS / BM) * (NO / BN)), dim3(256), 0,
                       stream, X, Wpk, Out);
}

// Round 5
// 315.538 us; speedup vs baseline: 2.1219x; 2.1219x over previous
//
#include <hip/hip_runtime.h>
#include <hip/hip_bf16.h>

// Grouped GEMM: out[e,s,o] = sum_i x[e,s,i] * w[e,o,i]
// E=8, S=8192 tok/expert, O=512, I=1024, fp32 in/out, bf16 MFMA compute.
// R5: barrier-free. No LDS. A fragments read reg-direct from global
//     (L1/L2-backed, 8x reuse absorbed by cache); B fragments reg-direct
//     from packed-bf16 Wpk in L2 (proven in R3). R4's spill (la+bfrA+bfrB
//     ~190 VGPR -> scratch, FETCH 145->901 MB) is structurally impossible
//     here: no staging arrays, ~150 VGPR peak.

#define NE 8
#define NO 512
#define NI 1024
#define NS 8192

#define BM 128
#define BN 128
#define BK 32
#define NT (NI / BK)  // 32 K-steps

typedef __attribute__((ext_vector_type(4))) float f32x4;
typedef __attribute__((ext_vector_type(8))) short short8;

__device__ __forceinline__ short8 cvt8(f32x4 a, f32x4 b) {
    short8 r;
    r[0] = (short)__builtin_bit_cast(unsigned short, __float2bfloat16(a[0]));
    r[1] = (short)__builtin_bit_cast(unsigned short, __float2bfloat16(a[1]));
    r[2] = (short)__builtin_bit_cast(unsigned short, __float2bfloat16(a[2]));
    r[3] = (short)__builtin_bit_cast(unsigned short, __float2bfloat16(a[3]));
    r[4] = (short)__builtin_bit_cast(unsigned short, __float2bfloat16(b[0]));
    r[5] = (short)__builtin_bit_cast(unsigned short, __float2bfloat16(b[1]));
    r[6] = (short)__builtin_bit_cast(unsigned short, __float2bfloat16(b[2]));
    r[7] = (short)__builtin_bit_cast(unsigned short, __float2bfloat16(b[3]));
    return r;
}

// ---- pass 0: W fp32 -> bf16, MFMA B-fragment lane order (verified R3) ----
// Wpk(e, g, kt32, l, j) = bf16(W[e][g*16 + (l&15)][kt32*32 + (l>>4)*8 + j])
__global__ __launch_bounds__(256)
void pack_w(const float* __restrict__ W, short* __restrict__ Wpk) {
    int idx  = blockIdx.x * 256 + threadIdx.x;  // 0 .. 524287
    int l    = idx & 63;
    int kt32 = (idx >> 6) & 31;
    int g    = (idx >> 11) & 31;
    int e    = idx >> 16;
    const float* src = W + (size_t)(e * NO + g * 16 + (l & 15)) * NI
                         + kt32 * 32 + (l >> 4) * 8;
    f32x4 a = *(const f32x4*)src;
    f32x4 b = *(const f32x4*)(src + 4);
    *(short8*)(Wpk + (size_t)idx * 8) = cvt8(a, b);
}

// ---- main grouped GEMM: no LDS, no barriers ----
__global__ __launch_bounds__(256, 3)
void moe_gemm(const float* __restrict__ X,
              const short* __restrict__ Wpk,
              float* __restrict__ Out) {
    // 2048 blocks; XCD-chunk swizzle: each XCD owns one expert.
    // nblk inner -> the 4 siblings sharing an A tile run concurrently on
    // the same XCD; their 8x A re-reads hit L1/L2.
    int bid  = blockIdx.x;
    int swz  = (bid & 7) * 256 + (bid >> 3);
    int e    = swz >> 8;
    int rem  = swz & 255;
    int mblk = rem >> 2;
    int nblk = rem & 3;

    const float* Ap = X   + ((size_t)e * NS + (size_t)mblk * BM) * NI;
    const short* Bp = Wpk + (size_t)e * (32 * 32 * 64 * 8);
    float*       Cp = Out + ((size_t)e * NS + (size_t)mblk * BM) * NO + nblk * BN;

    const int tid  = threadIdx.x;
    const int lane = tid & 63;
    const int wid  = tid >> 6;
    const int wr   = (wid >> 1) * 64;            // wave row base (2x2 wave grid)
    const int wc   = (wid & 1) * 64;             // wave col base
    const int wcg  = nblk * 8 + (wid & 1) * 4;   // B fragment-group base
    const int l15  = lane & 15;
    const int l4   = lane >> 4;

    f32x4 acc[4][4];
#pragma unroll
    for (int i = 0; i < 4; ++i)
#pragma unroll
        for (int j = 0; j < 4; ++j)
            acc[i][j] = (f32x4){0.f, 0.f, 0.f, 0.f};

    // Per-fragment A row pointers: lane reads row (wr+mi*16+l15),
    // cols kt*32 + l4*8 .. +7 (32 B contiguous, 2x f32x4).
    const float* arow[4];
#pragma unroll
    for (int mi = 0; mi < 4; ++mi)
        arow[mi] = Ap + (size_t)(wr + mi * 16 + l15) * NI + l4 * 8;

    // Per-lane B base: fragment (wcg+ni, kt) lives at ((wcg+ni)*32+kt)*512 shorts.
    const short* brow = Bp + (size_t)lane * 8;

#pragma unroll 2
    for (int kt = 0; kt < NT; ++kt) {
        short8 bfr[4];
#pragma unroll
        for (int ni = 0; ni < 4; ++ni)
            bfr[ni] = *(const short8*)(brow + ((size_t)((wcg + ni) * 32 + kt) * 512));

        short8 af[4];
#pragma unroll
        for (int mi = 0; mi < 4; ++mi) {
            const float* p = arow[mi] + kt * BK;
            f32x4 pa = *(const f32x4*)p;
            f32x4 pb = *(const f32x4*)(p + 4);
            af[mi] = cvt8(pa, pb);
        }

#pragma unroll
        for (int mi = 0; mi < 4; ++mi)
#pragma unroll
            for (int ni = 0; ni < 4; ++ni)
                acc[mi][ni] = __builtin_amdgcn_mfma_f32_16x16x32_bf16(
                    af[mi], bfr[ni], acc[mi][ni], 0, 0, 0);
    }

    // Epilogue: D[m][n], m = (lane>>4)*4 + r, n = lane&15 per 16x16 frag (verified).
#pragma unroll
    for (int mi = 0; mi < 4; ++mi) {
#pragma unroll
        for (int r = 0; r < 4; ++r) {
            int row   = wr + mi * 16 + l4 * 4 + r;
            float* cp = Cp + (size_t)row * NO + wc + l15;
#pragma unroll
            for (int ni = 0; ni < 4; ++ni)
                cp[ni * 16] = acc[mi][ni][r];
        }
    }
}

extern "C" void kernel_launch(void* const* d_in, const int* in_sizes, int n_in,
                              void* d_out, int out_size, void* d_ws, size_t ws_size,
                              hipStream_t stream) {
    const float* X = (const float*)d_in[0];
    const float* W = (const float*)d_in[1];
    float* Out     = (float*)d_out;
    short* Wpk     = (short*)d_ws;   // 8 MiB

    hipLaunchKernelGGL(pack_w, dim3(2048), dim3(256), 0, stream, W, Wpk);
    hipLaunchKernelGGL(moe_gemm, dim3(NE * (NS / BM) * (NO / BN)), dim3(256), 0,
                       stream, X, Wpk, Out);
}